// Round 12
// baseline (220.809 us; speedup 1.0000x reference)
//
#include <hip/hip_runtime.h>
#include <stdint.h>

// Fused 2-layer LSTM (B=32768, T=64, F=8, H=16) + FC(16->512,relu) + FC(512->32)
// SWAPPED-OPERAND design: A=weights [gate][k], B=inputs [k][batch], C=z^T.
// R8: recurrent h handoff via v_permlane32_swap_b32 (pure VALU, zero DS ops in
// the 64-step loop) using a re-chosen unit->k-slot map
//   unit(g,j) = 4*(g&1) + (j&3) + 8*(j>>2)
// so every exchange is an exact half<->half lane move. bf16 hi/lo Dekker split,
// fp32 MFMA accum.

#define NT 64
#define NF 8

typedef __attribute__((ext_vector_type(8))) short bf16x8;
typedef __attribute__((ext_vector_type(4))) float f32x4;
typedef __attribute__((ext_vector_type(2))) unsigned int u32x2;
typedef __attribute__((ext_vector_type(4))) unsigned int u32x4;

#define MFMA16 __builtin_amdgcn_mfma_f32_16x16x32_bf16

// packed bf16 pair: low16 = bf16(a), high16 = bf16(b). RNE in HW.
static __device__ __forceinline__ uint32_t cvt_pk(float a, float b) {
  uint32_t r;
  asm("v_cvt_pk_bf16_f32 %0, %1, %2" : "=v"(r) : "v"(a), "v"(b));
  return r;
}
static __device__ __forceinline__ void pack_hl(float a, float b,
                                               uint32_t& hi, uint32_t& lo) {
  hi = cvt_pk(a, b);
  float ha = __uint_as_float(hi << 16);          // bf16(a) as f32
  float hb = __uint_as_float(hi & 0xFFFF0000u);  // bf16(b) as f32
  lo = cvt_pk(a - ha, b - hb);
}
static __device__ __forceinline__ void split_hl(float f, short& hi, short& lo) {
  uint32_t w = cvt_pk(f, 0.f);
  hi = (short)(w & 0xFFFFu);
  float hf = __uint_as_float(w << 16);
  uint32_t wl = cvt_pk(f - hf, 0.f);
  lo = (short)(wl & 0xFFFFu);
}
static __device__ __forceinline__ float sigmoidf_(float v) {
  return __builtin_amdgcn_rcpf(1.0f + __expf(-v));
}
static __device__ __forceinline__ bf16x8 asbf(u32x4 w) {
  union { u32x4 u; bf16x8 b; } c; c.u = w; return c.b;
}
// v_permlane32_swap_b32: exchanges a's UPPER 32 lanes with b's LOWER 32 lanes.
// After: a = [a.lo | b.lo], b = [a.hi | b.hi]  (both outputs used).
static __device__ __forceinline__ void pl32(uint32_t& a, uint32_t& b) {
  asm("v_permlane32_swap_b32 %0, %1" : "+v"(a), "+v"(b));
}
static __device__ __forceinline__ void lds_fence() {
  asm volatile("s_waitcnt lgkmcnt(0)" ::: "memory");
}
// k-slot s=8g+j holds hidden unit 4*(g&1) + (j&3) + 8*(j>>2)
static __device__ __forceinline__ int unitmap(int g, int j) {
  return 4 * (g & 1) + (j & 3) + 8 * (j >> 2);
}

__global__ __launch_bounds__(256, 2) void lstm_fused(
    const float* __restrict__ x,
    const float* __restrict__ W1, const float* __restrict__ U1, const float* __restrict__ b1,
    const float* __restrict__ W2, const float* __restrict__ U2, const float* __restrict__ b2,
    const float* __restrict__ Wfc1, const float* __restrict__ bfc1,
    const float* __restrict__ Wfc2, const float* __restrict__ bfc2,
    float* __restrict__ out)
{
  const int tid  = threadIdx.x;
  const int lane = tid & 63;
  const int wv   = tid >> 6;
  const int col  = lane & 15;   // batch column (B-frag N / C-frag col)
  const int g    = lane >> 4;   // K-group (slots 8g..8g+7) / C-row group
  const int base = (blockIdx.x * 4 + wv) * 16;

  // FC1->FC2 staging only (stride 80B: 16B-aligned b128, banks spread)
  __shared__ __align__(16) char cf[4][2][16 * 80];
  char* const cfh = &cf[wv][0][0];
  char* const cfl = &cf[wv][1][0];

  // ---- static weight fragments (A-position), unit-mapped ----
  // L1: B1a = [W1h(xh) ; W1h(xl) ; U1h(pi)], B2a = [W1l ; 0 ; U1l(pi)]
  // L2: B1b = [W2h(pi) ; U2h(pi)],           B2b = [W2l(pi) ; U2l(pi)]
  bf16x8 B1a[4], B2a[4], B1b[4], B2b[4];
#pragma unroll
  for (int n = 0; n < 4; ++n) {
    const int c = 16 * n + col;
#pragma unroll
    for (int j = 0; j < 8; ++j) {
      const int u = unitmap(g, j);
      short h, l;
      if (g == 0)      { split_hl(W1[j * 64 + c], h, l); B1a[n][j] = h; B2a[n][j] = l; }
      else if (g == 1) { split_hl(W1[j * 64 + c], h, l); B1a[n][j] = h; B2a[n][j] = 0; }
      else             { split_hl(U1[u * 64 + c], h, l); B1a[n][j] = h; B2a[n][j] = l; }
      short h2, l2;
      if (g < 2) split_hl(W2[u * 64 + c], h2, l2);
      else       split_hl(U2[u * 64 + c], h2, l2);
      B1b[n][j] = h2; B2b[n][j] = l2;
    }
  }

  f32x4 bias1v[4], bias2v[4];
#pragma unroll
  for (int n = 0; n < 4; ++n) {
    bias1v[n] = *(const f32x4*)(b1 + 16 * n + 4 * g);
    bias2v[n] = *(const f32x4*)(b2 + 16 * n + 4 * g);
  }

  f32x4 c1 = {0.f, 0.f, 0.f, 0.f};
  f32x4 c2 = {0.f, 0.f, 0.f, 0.f};
  // packed h state: [0]=p01h [1]=p23h [2]=p01l [3]=p23l (lane holds units 4g..4g+3)
  uint32_t h1p[4] = {0, 0, 0, 0};
  uint32_t h2p[4] = {0, 0, 0, 0};

  const float* xrow = x + (size_t)(base + col) * (NT * NF);
  f32x4 xa = *(const f32x4*)(xrow);
  f32x4 xb = *(const f32x4*)(xrow + 4);

  // ================= merged recurrent loop: LSTM1(i) || LSTM2(i-1) ==========
  for (int i = 0; i < NT; ++i) {
    // x -> hi/lo packed words (features 2q,2q+1)
    uint32_t xh[4], xl[4];
    pack_hl(xa[0], xa[1], xh[0], xl[0]);
    pack_hl(xa[2], xa[3], xh[1], xl[1]);
    pack_hl(xb[0], xb[1], xh[2], xl[2]);
    pack_hl(xb[2], xb[3], xh[3], xl[3]);
    if (i + 1 < NT) {
      xa = *(const f32x4*)(xrow + (i + 1) * NF);
      xb = *(const f32x4*)(xrow + (i + 1) * NF + 4);
    }

    // ---- L1B1 = [xh | xl | h1h] via S-select + swap; L1B3 = [0 | 0 | h1l]
    uint32_t S0 = (g & 1) ? xl[0] : xh[0];
    { uint32_t t = (g & 1) ? xl[2] : xh[2]; S0 = (g & 2) ? t : S0; }
    uint32_t S1 = (g & 1) ? xl[1] : xh[1];
    { uint32_t t = (g & 1) ? xl[3] : xh[3]; S1 = (g & 2) ? t : S1; }
    uint32_t a0 = S0, a2 = h1p[0]; pl32(a0, a2);   // a0=[x.w0|P01] a2=[x.w2|P89...]
    uint32_t a1 = S1, a3 = h1p[1]; pl32(a1, a3);
    uint32_t e0 = 0,  e2 = h1p[2]; pl32(e0, e2);
    uint32_t e1 = 0,  e3 = h1p[3]; pl32(e1, e3);
    bf16x8 L1B1 = asbf((u32x4){a0, a1, a2, a3});
    bf16x8 L1B3 = asbf((u32x4){e0, e1, e2, e3});

    // ---- L2B1 = [h1h | h2h], L2B3 = [h1l | h2l] via direct h1xh2 swaps
    uint32_t m0 = h1p[0], m2 = h2p[0]; pl32(m0, m2);
    uint32_t m1 = h1p[1], m3 = h2p[1]; pl32(m1, m3);
    uint32_t n0 = h1p[2], n2 = h2p[2]; pl32(n0, n2);
    uint32_t n1 = h1p[3], n3 = h2p[3]; pl32(n1, n3);
    bf16x8 L2B1 = asbf((u32x4){m0, m1, m2, m3});
    bf16x8 L2B3 = asbf((u32x4){n0, n1, n2, n3});

    f32x4 z[4], y[4];
#pragma unroll
    for (int n = 0; n < 4; ++n) {
      f32x4 zi = MFMA16(B1a[n], L1B1, bias1v[n], 0, 0, 0);
      zi = MFMA16(B2a[n], L1B1, zi, 0, 0, 0);
      zi = MFMA16(B1a[n], L1B3, zi, 0, 0, 0);
      asm("" : "+v"(zi));                 // keep accumulator in arch VGPRs
      z[n] = zi;
      f32x4 yi = MFMA16(B1b[n], L2B1, bias2v[n], 0, 0, 0);
      yi = MFMA16(B2b[n], L2B1, yi, 0, 0, 0);
      yi = MFMA16(B1b[n], L2B3, yi, 0, 0, 0);
      asm("" : "+v"(yi));
      y[n] = yi;
    }

    // ---- LSTM1 gates -> h1(i) -> pack (state) ----
    f32x4 h1v;
#pragma unroll
    for (int r = 0; r < 4; ++r) {
      float ig = sigmoidf_(z[0][r]);
      float fg = sigmoidf_(z[1][r]);
      float gg = fmaxf(z[2][r], 0.f);
      float og = sigmoidf_(z[3][r]);
      float cc = fg * c1[r] + ig * gg;
      c1[r] = cc;
      h1v[r] = og * fmaxf(cc, 0.f);
    }
    pack_hl(h1v[0], h1v[1], h1p[0], h1p[2]);
    pack_hl(h1v[2], h1v[3], h1p[1], h1p[3]);

    // ---- LSTM2 gates -> h2(i-1) -> pack (state) ----
    f32x4 h2v;
    if (i != 0) {
#pragma unroll
      for (int r = 0; r < 4; ++r) {
        float ig = sigmoidf_(y[0][r]);
        float fg = sigmoidf_(y[1][r]);
        float gg = fmaxf(y[2][r], 0.f);
        float og = sigmoidf_(y[3][r]);
        float cc = fg * c2[r] + ig * gg;
        c2[r] = cc;
        h2v[r] = og * fmaxf(cc, 0.f);
      }
    } else {
      h2v = (f32x4){0.f, 0.f, 0.f, 0.f};
    }
    pack_hl(h2v[0], h2v[1], h2p[0], h2p[2]);
    pack_hl(h2v[2], h2v[3], h2p[1], h2p[3]);
  }

  // ---- epilogue: LSTM2(63) from h1(63) x h2(62) ----
  {
    uint32_t m0 = h1p[0], m2 = h2p[0]; pl32(m0, m2);
    uint32_t m1 = h1p[1], m3 = h2p[1]; pl32(m1, m3);
    uint32_t n0 = h1p[2], n2 = h2p[2]; pl32(n0, n2);
    uint32_t n1 = h1p[3], n3 = h2p[3]; pl32(n1, n3);
    bf16x8 L2B1 = asbf((u32x4){m0, m1, m2, m3});
    bf16x8 L2B3 = asbf((u32x4){n0, n1, n2, n3});
    f32x4 y[4];
#pragma unroll
    for (int n = 0; n < 4; ++n) {
      f32x4 yi = MFMA16(B1b[n], L2B1, bias2v[n], 0, 0, 0);
      yi = MFMA16(B2b[n], L2B1, yi, 0, 0, 0);
      yi = MFMA16(B1b[n], L2B3, yi, 0, 0, 0);
      y[n] = yi;
    }
    f32x4 h2v;
#pragma unroll
    for (int r = 0; r < 4; ++r) {
      float ig = sigmoidf_(y[0][r]);
      float fg = sigmoidf_(y[1][r]);
      float gg = fmaxf(y[2][r], 0.f);
      float og = sigmoidf_(y[3][r]);
      float cc = fg * c2[r] + ig * gg;
      c2[r] = cc;
      h2v[r] = og * fmaxf(cc, 0.f);
    }
    pack_hl(h2v[0], h2v[1], h2p[0], h2p[2]);
    pack_hl(h2v[2], h2v[3], h2p[1], h2p[3]);
  }

  // ================= FC head =================
  // Bfc: K = [h2hi(16) | h2lo(16)], unit-mapped; built by hi x lo swaps
  uint32_t f0 = h2p[0], f2 = h2p[2]; pl32(f0, f2);
  uint32_t f1 = h2p[1], f3 = h2p[3]; pl32(f1, f3);
  bf16x8 Bfc = asbf((u32x4){f0, f1, f2, f3});

  f32x4 acc2[2];
#pragma unroll
  for (int nn = 0; nn < 2; ++nn)
    acc2[nn] = *(const f32x4*)(bfc2 + 16 * nn + 4 * g);

  for (int kc = 0; kc < 16; ++kc) {
#pragma unroll
    for (int t = 0; t < 2; ++t) {
      const int mt = 2 * kc + t;
      bf16x8 A1h, A1l;
#pragma unroll
      for (int j = 0; j < 8; ++j) {
        float w = Wfc1[unitmap(g, j) * 512 + 16 * mt + col];
        short h, l; split_hl(w, h, l);
        A1h[j] = h; A1l[j] = l;
      }
      f32x4 bv = *(const f32x4*)(bfc1 + 16 * mt + 4 * g);
      f32x4 acc = MFMA16(A1h, Bfc, bv, 0, 0, 0);
      acc = MFMA16(A1l, Bfc, acc, 0, 0, 0);
      uint32_t q01h, q01l, q23h, q23l;
      pack_hl(fmaxf(acc[0], 0.f), fmaxf(acc[1], 0.f), q01h, q01l);
      pack_hl(fmaxf(acc[2], 0.f), fmaxf(acc[3], 0.f), q23h, q23l);
      *(u32x2*)(cfh + col * 80 + 32 * t + 8 * g) = (u32x2){q01h, q23h};
      *(u32x2*)(cfl + col * 80 + 32 * t + 8 * g) = (u32x2){q01l, q23l};
    }
    lds_fence();
    bf16x8 Bh = *(const bf16x8*)(cfh + col * 80 + 16 * g);
    bf16x8 Bl = *(const bf16x8*)(cfl + col * 80 + 16 * g);
#pragma unroll
    for (int nn = 0; nn < 2; ++nn) {
      bf16x8 A2h, A2l;
#pragma unroll
      for (int j = 0; j < 8; ++j) {
        float w = Wfc2[(size_t)(32 * kc + 8 * g + j) * 32 + 16 * nn + col];
        short h, l; split_hl(w, h, l);
        A2h[j] = h; A2l[j] = l;
      }
      acc2[nn] = MFMA16(A2h, Bh, acc2[nn], 0, 0, 0);
      acc2[nn] = MFMA16(A2h, Bl, acc2[nn], 0, 0, 0);
      acc2[nn] = MFMA16(A2l, Bh, acc2[nn], 0, 0, 0);
    }
    lds_fence();   // WAR: next kc overwrites staging
  }

  // out[b][32]: lane(col,g) holds rows 16nn+4g+r of batch base+col
#pragma unroll
  for (int nn = 0; nn < 2; ++nn)
    *(f32x4*)(out + (size_t)(base + col) * 32 + 16 * nn + 4 * g) = acc2[nn];
}

extern "C" void kernel_launch(void* const* d_in, const int* in_sizes, int n_in,
                              void* d_out, int out_size, void* d_ws, size_t ws_size,
                              hipStream_t stream) {
  const float* x    = (const float*)d_in[0];
  const float* W1   = (const float*)d_in[1];
  const float* U1   = (const float*)d_in[2];
  const float* b1   = (const float*)d_in[3];
  const float* W2   = (const float*)d_in[4];
  const float* U2   = (const float*)d_in[5];
  const float* b2   = (const float*)d_in[6];
  const float* Wfc1 = (const float*)d_in[7];
  const float* bfc1 = (const float*)d_in[8];
  const float* Wfc2 = (const float*)d_in[9];
  const float* bfc2 = (const float*)d_in[10];

  lstm_fused<<<dim3(512), dim3(256), 0, stream>>>(
      x, W1, U1, b1, W2, U2, b2, Wfc1, bfc1, Wfc2, bfc2, (float*)d_out);
}